// Round 1
// baseline (180.672 us; speedup 1.0000x reference)
//
#include <hip/hip_runtime.h>
#include <math.h>

// ---- compile-time physical constants (mirror the Python reference) ----
namespace k {
constexpr double dA     = 0.129907 + 0.095724;       // L_X + L_Y
constexpr double dR     = 4.0 * 0.0254;              // wheel radius
constexpr double dI     = 6.0;                       // inertia (== mass)
constexpr double dMOI   = 6.0 * (12.0 * 0.0254) * (12.0 * 0.0254) / 6.0;
constexpr float T_STALL   = (float)(5.4 / 100.0);
constexpr float INV_WFREE = (float)(1.0 / (1620.0 / 60.0 * 2.0 * 3.14159265358979323846));
constexpr float A         = (float)dA;
constexpr float INV_R     = (float)(1.0 / dR);
constexpr float INV_RI    = (float)(1.0 / (dR * dI));    // WT2LA rows 0,1 scale
constexpr float A_RMOI    = (float)(dA / (dR * dMOI));   // WT2LA row 2 scale
}

__device__ __forceinline__ float wheel_torque(float w, float m) {
    float p = m * w;
    // jnp.sign semantics: sign(0)=0 -> is_same_direction = 0.5
    float sgn = (float)(p > 0.0f) - (float)(p < 0.0f);
    float isd = 0.5f * (sgn + 1.0f);
    return k::T_STALL * (1.0f - fabsf(w) * isd * k::INV_WFREE) * m;
}

// One batch element: st[0..5] = state row, m0..m3 = motor duty, o[0..5] = out row
__device__ __forceinline__ void mecanum_elem(const float st[6],
                                             float m0, float m1, float m2, float m3,
                                             float o[6]) {
    float theta = st[2];
    float s, c;
    sincosf(theta, &s, &c);

    float v0 = st[3], v1 = st[4], v2 = st[5];

    // a2l = rot(cos(-t), sin(-t)) -> [[c, s, 0], [-s, c, 0], [0,0,1]]
    float lv0 = c * v0 + s * v1;
    float lv1 = c * v1 - s * v0;
    float lv2 = v2;

    // wheel_vel = LV2WV @ local_vel, LV2WV rows: [1,-1,-A],[1,1,A],[1,1,-A],[1,-1,A], all /R
    float al2 = k::A * lv2;
    float w0 = (lv0 - lv1 - al2) * k::INV_R;
    float w1 = (lv0 + lv1 + al2) * k::INV_R;
    float w2 = (lv0 + lv1 - al2) * k::INV_R;
    float w3 = (lv0 - lv1 + al2) * k::INV_R;

    float t0 = wheel_torque(w0, m0);
    float t1 = wheel_torque(w1, m1);
    float t2 = wheel_torque(w2, m2);
    float t3 = wheel_torque(w3, m3);

    // local_accel = WT2LA @ torque
    float la0 = (t0 + t1 + t2 + t3) * k::INV_RI;
    float la1 = (-t0 + t1 + t2 - t3) * k::INV_RI;
    float la2 = (-t0 + t1 - t2 + t3) * k::A_RMOI;

    // l2a = rot(cos(t), sin(t)) -> [[c,-s,0],[s,c,0],[0,0,1]]
    float aa0 = c * la0 - s * la1;
    float aa1 = s * la0 + c * la1;

    o[0] = v0; o[1] = v1; o[2] = v2;
    o[3] = aa0; o[4] = aa1; o[5] = la2;
}

// Two elements per thread: 48 B = 3 x float4, 16B-aligned, coalesced.
__global__ __launch_bounds__(256) void mecanum_pair_kernel(
    const float4* __restrict__ state4,
    const float* __restrict__ cd,
    float4* __restrict__ out4,
    int n_pairs) {
    int i = blockIdx.x * blockDim.x + threadIdx.x;
    if (i >= n_pairs) return;

    // batch-uniform motor duty: CD2MD @ control_duty
    float u0 = cd[0], u1 = cd[1], u2 = cd[2];
    float m0 = u0 - u1 - u2;
    float m1 = u0 + u1 + u2;
    float m2 = u0 + u1 - u2;
    float m3 = u0 - u1 + u2;

    float4 a = state4[3 * i + 0];
    float4 b = state4[3 * i + 1];
    float4 g = state4[3 * i + 2];

    float stA[6] = { a.x, a.y, a.z, a.w, b.x, b.y };
    float stB[6] = { b.z, b.w, g.x, g.y, g.z, g.w };
    float oA[6], oB[6];
    mecanum_elem(stA, m0, m1, m2, m3, oA);
    mecanum_elem(stB, m0, m1, m2, m3, oB);

    float4 r0 = { oA[0], oA[1], oA[2], oA[3] };
    float4 r1 = { oA[4], oA[5], oB[0], oB[1] };
    float4 r2 = { oB[2], oB[3], oB[4], oB[5] };
    out4[3 * i + 0] = r0;
    out4[3 * i + 1] = r1;
    out4[3 * i + 2] = r2;
}

// Scalar tail for odd batch sizes (not expected for BATCH=4M; defensive only).
__global__ void mecanum_tail_kernel(const float* __restrict__ state,
                                    const float* __restrict__ cd,
                                    float* __restrict__ out,
                                    int start, int n) {
    int i = start + blockIdx.x * blockDim.x + threadIdx.x;
    if (i >= n) return;
    float u0 = cd[0], u1 = cd[1], u2 = cd[2];
    float m0 = u0 - u1 - u2;
    float m1 = u0 + u1 + u2;
    float m2 = u0 + u1 - u2;
    float m3 = u0 - u1 + u2;
    float st[6], o[6];
#pragma unroll
    for (int j = 0; j < 6; ++j) st[j] = state[6 * i + j];
    mecanum_elem(st, m0, m1, m2, m3, o);
#pragma unroll
    for (int j = 0; j < 6; ++j) out[6 * i + j] = o[j];
}

extern "C" void kernel_launch(void* const* d_in, const int* in_sizes, int n_in,
                              void* d_out, int out_size, void* d_ws, size_t ws_size,
                              hipStream_t stream) {
    // inputs: d_in[0] = t (1, unused), d_in[1] = state (BATCH*6), d_in[2] = control_duty (3)
    const float* state = (const float*)d_in[1];
    const float* cd    = (const float*)d_in[2];
    float* out         = (float*)d_out;

    int n = in_sizes[1] / 6;        // batch size
    int n_pairs = n / 2;

    if (n_pairs > 0) {
        int block = 256;
        int grid = (n_pairs + block - 1) / block;
        mecanum_pair_kernel<<<grid, block, 0, stream>>>(
            (const float4*)state, cd, (float4*)out, n_pairs);
    }
    if (n & 1) {
        mecanum_tail_kernel<<<1, 64, 0, stream>>>(state, cd, out, 2 * n_pairs, n);
    }
}

// Round 2
// 174.757 us; speedup vs baseline: 1.0338x; 1.0338x over previous
//
#include <hip/hip_runtime.h>
#include <math.h>

// ---- compile-time physical constants (mirror the Python reference) ----
namespace k {
constexpr double dA     = 0.129907 + 0.095724;       // L_X + L_Y
constexpr double dR     = 4.0 * 0.0254;              // wheel radius
constexpr double dI     = 6.0;                       // inertia (== mass)
constexpr double dMOI   = 6.0 * (12.0 * 0.0254) * (12.0 * 0.0254) / 6.0;
constexpr float T_STALL   = (float)(5.4 / 100.0);
constexpr float INV_WFREE = (float)(1.0 / (1620.0 / 60.0 * 2.0 * 3.14159265358979323846));
constexpr float A         = (float)dA;
constexpr float INV_R     = (float)(1.0 / dR);
constexpr float INV_RI    = (float)(1.0 / (dR * dI));    // WT2LA rows 0,1 scale
constexpr float A_RMOI    = (float)(dA / (dR * dMOI));   // WT2LA row 2 scale
}

__device__ __forceinline__ float wheel_torque(float w, float m) {
    float p = m * w;
    // jnp.sign semantics: sign(0)=0 -> is_same_direction = 0.5
    float sgn = (float)(p > 0.0f) - (float)(p < 0.0f);
    float isd = 0.5f * (sgn + 1.0f);
    return k::T_STALL * (1.0f - fabsf(w) * isd * k::INV_WFREE) * m;
}

// One batch element: st[0..5] = state row, m0..m3 = motor duty, o[0..5] = out row
__device__ __forceinline__ void mecanum_elem(const float st[6],
                                             float m0, float m1, float m2, float m3,
                                             float o[6]) {
    float theta = st[2];
    float s, c;
    sincosf(theta, &s, &c);

    float v0 = st[3], v1 = st[4], v2 = st[5];

    // a2l = rot(cos(-t), sin(-t)) -> [[c, s, 0], [-s, c, 0], [0,0,1]]
    float lv0 = c * v0 + s * v1;
    float lv1 = c * v1 - s * v0;

    // wheel_vel = LV2WV @ local_vel; rows [1,-1,-A],[1,1,A],[1,1,-A],[1,-1,A], /R
    float al2 = k::A * v2;
    float w0 = (lv0 - lv1 - al2) * k::INV_R;
    float w1 = (lv0 + lv1 + al2) * k::INV_R;
    float w2 = (lv0 + lv1 - al2) * k::INV_R;
    float w3 = (lv0 - lv1 + al2) * k::INV_R;

    float t0 = wheel_torque(w0, m0);
    float t1 = wheel_torque(w1, m1);
    float t2 = wheel_torque(w2, m2);
    float t3 = wheel_torque(w3, m3);

    // local_accel = WT2LA @ torque
    float la0 = (t0 + t1 + t2 + t3) * k::INV_RI;
    float la1 = (-t0 + t1 + t2 - t3) * k::INV_RI;
    float la2 = (-t0 + t1 - t2 + t3) * k::A_RMOI;

    // l2a = rot(cos(t), sin(t)) -> [[c,-s,0],[s,c,0],[0,0,1]]
    float aa0 = c * la0 - s * la1;
    float aa1 = s * la0 + c * la1;

    o[0] = st[3]; o[1] = st[4]; o[2] = st[5];
    o[3] = aa0; o[4] = aa1; o[5] = la2;
}

// Block = 256 threads, 512 elements (pairs), 768 float4 in / 768 float4 out.
// All global traffic is lane-consecutive float4 (perfect coalescing); the
// 48 B-stride gather/scatter happens in LDS instead of at the L1/TA.
#define PAIRS_PER_BLOCK 256
#define F4_PER_BLOCK    (PAIRS_PER_BLOCK * 3)

__global__ __launch_bounds__(256) void mecanum_lds_kernel(
    const float4* __restrict__ state4,
    const float* __restrict__ cd,
    float4* __restrict__ out4,
    int n_pairs) {
    __shared__ float4 s_in[F4_PER_BLOCK];
    __shared__ float4 s_out[F4_PER_BLOCK];

    const int tid = threadIdx.x;
    const int pair_base = blockIdx.x * PAIRS_PER_BLOCK;
    const int f4_base = pair_base * 3;
    const int total4 = n_pairs * 3;

    // ---- coalesced load: lane-consecutive float4 ----
#pragma unroll
    for (int j = 0; j < 3; ++j) {
        int g = f4_base + j * 256 + tid;
        if (g < total4) s_in[j * 256 + tid] = state4[g];
    }

    // batch-uniform motor duty: CD2MD @ control_duty (wave-uniform loads)
    float u0 = cd[0], u1 = cd[1], u2 = cd[2];
    float m0 = u0 - u1 - u2;
    float m1 = u0 + u1 + u2;
    float m2 = u0 + u1 - u2;
    float m3 = u0 - u1 + u2;

    __syncthreads();

    // ---- compute this thread's element pair from LDS ----
    if (pair_base + tid < n_pairs) {
        float4 a = s_in[3 * tid + 0];
        float4 b = s_in[3 * tid + 1];
        float4 g = s_in[3 * tid + 2];

        float stA[6] = { a.x, a.y, a.z, a.w, b.x, b.y };
        float stB[6] = { b.z, b.w, g.x, g.y, g.z, g.w };
        float oA[6], oB[6];
        mecanum_elem(stA, m0, m1, m2, m3, oA);
        mecanum_elem(stB, m0, m1, m2, m3, oB);

        s_out[3 * tid + 0] = make_float4(oA[0], oA[1], oA[2], oA[3]);
        s_out[3 * tid + 1] = make_float4(oA[4], oA[5], oB[0], oB[1]);
        s_out[3 * tid + 2] = make_float4(oB[2], oB[3], oB[4], oB[5]);
    }

    __syncthreads();

    // ---- coalesced store ----
#pragma unroll
    for (int j = 0; j < 3; ++j) {
        int g = f4_base + j * 256 + tid;
        if (g < total4) out4[g] = s_out[j * 256 + tid];
    }
}

// Scalar tail for odd batch sizes (defensive; BATCH=4M is even).
__global__ void mecanum_tail_kernel(const float* __restrict__ state,
                                    const float* __restrict__ cd,
                                    float* __restrict__ out,
                                    int start, int n) {
    int i = start + blockIdx.x * blockDim.x + threadIdx.x;
    if (i >= n) return;
    float u0 = cd[0], u1 = cd[1], u2 = cd[2];
    float m0 = u0 - u1 - u2;
    float m1 = u0 + u1 + u2;
    float m2 = u0 + u1 - u2;
    float m3 = u0 - u1 + u2;
    float st[6], o[6];
#pragma unroll
    for (int j = 0; j < 6; ++j) st[j] = state[6 * i + j];
    mecanum_elem(st, m0, m1, m2, m3, o);
#pragma unroll
    for (int j = 0; j < 6; ++j) out[6 * i + j] = o[j];
}

extern "C" void kernel_launch(void* const* d_in, const int* in_sizes, int n_in,
                              void* d_out, int out_size, void* d_ws, size_t ws_size,
                              hipStream_t stream) {
    // inputs: d_in[0] = t (1, unused), d_in[1] = state (BATCH*6), d_in[2] = control_duty (3)
    const float* state = (const float*)d_in[1];
    const float* cd    = (const float*)d_in[2];
    float* out         = (float*)d_out;

    int n = in_sizes[1] / 6;        // batch size
    int n_pairs = n / 2;

    if (n_pairs > 0) {
        int grid = (n_pairs + PAIRS_PER_BLOCK - 1) / PAIRS_PER_BLOCK;
        mecanum_lds_kernel<<<grid, 256, 0, stream>>>(
            (const float4*)state, cd, (float4*)out, n_pairs);
    }
    if (n & 1) {
        mecanum_tail_kernel<<<1, 64, 0, stream>>>(state, cd, out, 2 * n_pairs, n);
    }
}